// Round 3
// baseline (1248.270 us; speedup 1.0000x reference)
//
#include <hip/hip_runtime.h>
#include <stdint.h>

// MemoryGateBlock fully-fused implementation (MI355X / gfx950)
// B=32768, M=10, D=256, H=256, NH=8, HD=32
//
//  k_prep  : f32 weights -> bf16, pre-swizzled into MFMA B-fragment order (ws ~1.32MB)
//  k_fused : per 8-batch block (80 memory rows), entirely in LDS:
//            G=cur@Wcur -> z,r -> cand -> upd -> kproj -> softmax -> weighted
//            -> Wo GEMM -> LayerNorm.  Writes fused, upd, attn_weights.
//
// d_out layout (f32): fused[32768*256] | upd[32768*10*256] | aw[32768*10]

#define BB 32768
#define MM 10

typedef __attribute__((ext_vector_type(8))) short short8;
typedef __attribute__((ext_vector_type(4))) float f32x4;

// ws layout: wsW (655360 ushort = 1310720 B) | bias4 (1024 f32)
#define OFF_B4 1310720ull

__device__ __forceinline__ unsigned short f2bf(float f) {
  unsigned u = __builtin_bit_cast(unsigned, f);
  u += 0x7FFFu + ((u >> 16) & 1u);        // RNE
  return (unsigned short)(u >> 16);
}
__device__ __forceinline__ float bf2f(unsigned short h) {
  unsigned u = ((unsigned)h) << 16;
  return __builtin_bit_cast(float, u);
}
// ushort-index into a [rows][256] bf16 LDS tile, XOR-swizzled (byte ^= (row&7)<<4)
__device__ __forceinline__ int aidx(int r, int c)   { return (r * 256 + c) ^ ((r & 7) << 3); }
// same for [rows][512]
__device__ __forceinline__ int aidx512(int r, int c){ return (r * 512 + c) ^ ((r & 7) << 3); }

__device__ __forceinline__ float sigm(float x) { return 1.f / (1.f + __expf(-x)); }
__device__ __forceinline__ float tanh_f(float x) {
  float t = __expf(-2.f * fabsf(x));
  float r = (1.f - t) / (1.f + t);
  return x >= 0.f ? r : -r;
}

// ---------------- prep: weights -> bf16 MFMA B-fragment layout ----------------
// B-fragment for mfma_f32_16x16x32_bf16:
//   elem((ct*K32 + kk)*64 + lane)*8 + j  =  W[k = kk*32 + (lane>>4)*8 + j][n = ct*16 + (lane&15)]
// wsW sections (ushort offsets): Wcur@0 (256x1024) | Wzr@262144 (256x512) |
//   Wh2@393216 (256x256) | Wk@458752 (256x256) | Wo@524288 (512x256)
__global__ void k_prep(const float* __restrict__ Wz, const float* __restrict__ Wr,
                       const float* __restrict__ Wh, const float* __restrict__ Wq,
                       const float* __restrict__ Wk, const float* __restrict__ Wo,
                       const float* __restrict__ bz, const float* __restrict__ br,
                       const float* __restrict__ bh, const float* __restrict__ bq,
                       unsigned short* __restrict__ wsW, float* __restrict__ bias4) {
  int e = blockIdx.x * blockDim.x + threadIdx.x;
  if (e < 655360) {
    int e_l, mat;
    if (e < 262144)      { mat = 0; e_l = e; }            // Wcur 256x1024
    else if (e < 393216) { mat = 1; e_l = e - 262144; }   // Wzr  256x512
    else if (e < 458752) { mat = 2; e_l = e - 393216; }   // Wh2  256x256
    else if (e < 524288) { mat = 3; e_l = e - 458752; }   // Wk   256x256
    else                 { mat = 4; e_l = e - 524288; }   // Wo   512x256
    int K32 = (mat == 4) ? 16 : 8;
    int perct = K32 * 512;
    int ct = e_l / perct;
    int r  = e_l % perct;
    int kk = r >> 9;
    int r2 = r & 511;
    int lane = r2 >> 3, j = r2 & 7;
    int k = kk * 32 + ((lane >> 4) << 3) + j;
    int n = (ct << 4) + (lane & 15);
    float v;
    if (mat == 0) {
      v = (n < 256) ? Wz[k * 256 + n]
        : (n < 512) ? Wr[k * 256 + n - 256]
        : (n < 768) ? Wh[k * 256 + n - 512]
                    : Wq[k * 256 + n - 768];
    } else if (mat == 1) {
      v = (n < 256) ? Wz[(256 + k) * 256 + n] : Wr[(256 + k) * 256 + n - 256];
    } else if (mat == 2) {
      v = Wh[(256 + k) * 256 + n];
    } else if (mat == 3) {
      v = Wk[k * 256 + n];
    } else {
      v = Wo[k * 256 + n];
    }
    wsW[e] = f2bf(v);
  } else if (e < 656384) {
    int i = e - 655360;
    float v = (i < 256) ? bz[i] : (i < 512) ? br[i - 256] : (i < 768) ? bh[i - 512] : bq[i - 768];
    bias4[i] = v;
  }
}

// ---------------- fully fused kernel: one block = 8 batches (80 rows) ----------------
// LDS: smPm 40960 + smB2 40960 + smZ 40960 + smG 16384 + smF 16384 + smAw 384 = 152.4 KB
__global__ __launch_bounds__(512, 2) void k_fused(
    const float* __restrict__ cur, const float* __restrict__ pm,
    const unsigned short* __restrict__ wsW, const float* __restrict__ bias4,
    const float* __restrict__ bk, const float* __restrict__ bo,
    const float* __restrict__ gamma, const float* __restrict__ beta,
    float* __restrict__ outF, float* __restrict__ outUpd, float* __restrict__ outAw) {
  __shared__ unsigned short smPm[80 * 256];   // pm bf16 (swz); later aliased as f32 Y[8][256]
  __shared__ unsigned short smB2[80 * 256];   // r*pm -> upd bf16 (swz)
  __shared__ unsigned short smZ[80 * 256];    // z    -> kproj   (swz)
  __shared__ unsigned short smG[8 * 1024];    // per-batch cur-projections, linear [8][1024]
  __shared__ unsigned short smF[16 * 512];    // Wo A-tile [16][512] swz512: rows<8 = [cur|wm], rows>=8 = 0
  __shared__ float smAw[8][12];
  const int t = threadIdx.x, w = t >> 6, l = t & 63;
  const int b0 = blockIdx.x << 3;
  const size_t row0g = (size_t)b0 * MM;
  const unsigned short* Wcur = wsW;
  const unsigned short* Wzr  = wsW + 262144;
  const unsigned short* Wh2  = wsW + 393216;
  const unsigned short* Wkp  = wsW + 458752;
  const unsigned short* Wop  = wsW + 524288;

  // ---- P0: stage pm (f32->bf16 swz), cur -> smF rows 0..7 cols 0..255, zero smF rows 8..15 ----
  #pragma unroll
  for (int i = 0; i < 5; i++) {
    int chunk = (i << 9) + t;               // 2560 chunks of 8 elems
    int row = chunk >> 5, c8 = (chunk & 31) << 3;
    const float* s = pm + (row0g + row) * 256 + c8;
    float4 v0 = *(const float4*)s;
    float4 v1 = *(const float4*)(s + 4);
    uint4 pk;
    pk.x = f2bf(v0.x) | ((unsigned)f2bf(v0.y) << 16);
    pk.y = f2bf(v0.z) | ((unsigned)f2bf(v0.w) << 16);
    pk.z = f2bf(v1.x) | ((unsigned)f2bf(v1.y) << 16);
    pk.w = f2bf(v1.z) | ((unsigned)f2bf(v1.w) << 16);
    *(uint4*)&smPm[aidx(row, c8)] = pk;
  }
  if (t < 256) {                            // cur rows 0..7 (8*256 = 256 chunks of 8)
    int row = t >> 5, c8 = (t & 31) << 3;
    const float* s = cur + (size_t)(b0 + row) * 256 + c8;
    float4 v0 = *(const float4*)s;
    float4 v1 = *(const float4*)(s + 4);
    uint4 pk;
    pk.x = f2bf(v0.x) | ((unsigned)f2bf(v0.y) << 16);
    pk.y = f2bf(v0.z) | ((unsigned)f2bf(v0.w) << 16);
    pk.z = f2bf(v1.x) | ((unsigned)f2bf(v1.y) << 16);
    pk.w = f2bf(v1.z) | ((unsigned)f2bf(v1.w) << 16);
    *(uint4*)&smF[aidx512(row, c8)] = pk;
  } else {                                  // zero rows 8..15 (4096 ushorts, 256 thr x 16)
    int i = t - 256;
    uint4 z4 = {0u, 0u, 0u, 0u};
    *(uint4*)&smF[4096 + i * 16] = z4;
    *(uint4*)&smF[4096 + i * 16 + 8] = z4;
  }
  __syncthreads();

  // ---- P1: G = cur @ Wcur + bias4  (M=16 tile, rows 8..15 discarded) -> smG bf16 ----
  {
    f32x4 acc[8] = {};
    #pragma unroll
    for (int k = 0; k < 8; k++) {
      short8 a = *(const short8*)&smF[aidx512(l & 15, (k << 5) + ((l >> 4) << 3))];
      #pragma unroll
      for (int i = 0; i < 8; i++) {
        short8 b = *(const short8*)&Wcur[(size_t)(((w * 8 + i) * 8 + k) * 64 + l) * 8];
        acc[i] = __builtin_amdgcn_mfma_f32_16x16x32_bf16(a, b, acc[i], 0, 0, 0);
      }
    }
    const int rloc = (l >> 4) << 2;
    #pragma unroll
    for (int i = 0; i < 8; i++) {
      int col = ((w * 8 + i) << 4) + (l & 15);    // 0..1023
      float bia = bias4[col];
      #pragma unroll
      for (int reg = 0; reg < 4; reg++) {
        int row = rloc + reg;
        if (row < 8) smG[row * 1024 + col] = f2bf(acc[i][reg] + bia);
      }
    }
  }
  __syncthreads();

  // ---- P2: [80,256] @ Wzr[256,512]; epilogue -> z (smZ), r*pm (smB2) ----
  {
    f32x4 acc[5][4] = {};
    const int ctb = w << 2;                 // waves 0-3: z cols; waves 4-7: r cols
    #pragma unroll
    for (int k = 0; k < 8; k++) {
      short8 a[5], b[4];
      #pragma unroll
      for (int rt = 0; rt < 5; rt++)
        a[rt] = *(const short8*)&smPm[aidx((rt << 4) + (l & 15), (k << 5) + ((l >> 4) << 3))];
      #pragma unroll
      for (int i = 0; i < 4; i++)
        b[i] = *(const short8*)&Wzr[(size_t)(((ctb + i) * 8 + k) * 64 + l) * 8];
      #pragma unroll
      for (int rt = 0; rt < 5; rt++)
        #pragma unroll
        for (int i = 0; i < 4; i++)
          acc[rt][i] = __builtin_amdgcn_mfma_f32_16x16x32_bf16(a[rt], b[i], acc[rt][i], 0, 0, 0);
    }
    #pragma unroll
    for (int rt = 0; rt < 5; rt++) {
      #pragma unroll
      for (int i = 0; i < 4; i++) {
        const int col = ((ctb + i) << 4) + (l & 15);   // 0..511
        #pragma unroll
        for (int reg = 0; reg < 4; reg++) {
          const int row = (rt << 4) + ((l >> 4) << 2) + reg;
          const int bl = row / 10;
          float v = acc[rt][i][reg] + bf2f(smG[bl * 1024 + col]);
          float s = sigm(v);
          if (w < 4) {
            smZ[aidx(row, col)] = f2bf(s);
          } else {
            int cr = col - 256;
            float pmv = bf2f(smPm[aidx(row, cr)]);
            smB2[aidx(row, cr)] = f2bf(s * pmv);
          }
        }
      }
    }
  }
  __syncthreads();

  // ---- P3: cand = tanh(rp @ Wh2 + Gh); upd = (1-z)*pm_f32 + z*cand ----
  {
    f32x4 acc[5][2] = {};
    const int ctb = w << 1;
    #pragma unroll
    for (int k = 0; k < 8; k++) {
      short8 a[5], b[2];
      #pragma unroll
      for (int rt = 0; rt < 5; rt++)
        a[rt] = *(const short8*)&smB2[aidx((rt << 4) + (l & 15), (k << 5) + ((l >> 4) << 3))];
      #pragma unroll
      for (int i = 0; i < 2; i++)
        b[i] = *(const short8*)&Wh2[(size_t)(((ctb + i) * 8 + k) * 64 + l) * 8];
      #pragma unroll
      for (int rt = 0; rt < 5; rt++)
        #pragma unroll
        for (int i = 0; i < 2; i++)
          acc[rt][i] = __builtin_amdgcn_mfma_f32_16x16x32_bf16(a[rt], b[i], acc[rt][i], 0, 0, 0);
    }
    __syncthreads();   // all rp reads done before smB2 overwrite
    #pragma unroll
    for (int rt = 0; rt < 5; rt++) {
      #pragma unroll
      for (int i = 0; i < 2; i++) {
        const int col = ((ctb + i) << 4) + (l & 15);   // 0..255
        #pragma unroll
        for (int reg = 0; reg < 4; reg++) {
          const int row = (rt << 4) + ((l >> 4) << 2) + reg;
          const int bl = row / 10;
          float cnd = tanh_f(acc[rt][i][reg] + bf2f(smG[bl * 1024 + 512 + col]));
          float zv = bf2f(smZ[aidx(row, col)]);
          float pmv = pm[(row0g + row) * 256 + col];   // f32 (L2-hot)
          float u = (1.f - zv) * pmv + zv * cnd;
          outUpd[(row0g + row) * 256 + col] = u;
          smB2[aidx(row, col)] = f2bf(u);
        }
      }
    }
  }
  __syncthreads();

  // ---- P4: kproj = upd @ Wk + bk -> smZ ----
  {
    f32x4 acc[5][2] = {};
    const int ctb = w << 1;
    #pragma unroll
    for (int k = 0; k < 8; k++) {
      short8 a[5], b[2];
      #pragma unroll
      for (int rt = 0; rt < 5; rt++)
        a[rt] = *(const short8*)&smB2[aidx((rt << 4) + (l & 15), (k << 5) + ((l >> 4) << 3))];
      #pragma unroll
      for (int i = 0; i < 2; i++)
        b[i] = *(const short8*)&Wkp[(size_t)(((ctb + i) * 8 + k) * 64 + l) * 8];
      #pragma unroll
      for (int rt = 0; rt < 5; rt++)
        #pragma unroll
        for (int i = 0; i < 2; i++)
          acc[rt][i] = __builtin_amdgcn_mfma_f32_16x16x32_bf16(a[rt], b[i], acc[rt][i], 0, 0, 0);
    }
    float bkv0 = bk[(ctb << 4) + (l & 15)];
    float bkv1 = bk[((ctb + 1) << 4) + (l & 15)];
    #pragma unroll
    for (int rt = 0; rt < 5; rt++) {
      #pragma unroll
      for (int i = 0; i < 2; i++) {
        const int col = ((ctb + i) << 4) + (l & 15);
        const float bb = i ? bkv1 : bkv0;
        #pragma unroll
        for (int reg = 0; reg < 4; reg++) {
          const int row = (rt << 4) + ((l >> 4) << 2) + reg;
          smZ[aidx(row, col)] = f2bf(acc[rt][i][reg] + bb);
        }
      }
    }
  }
  __syncthreads();

  // ---- P5: scores / softmax / head-avg (wave w <-> batch w) ----
  {
    const int n = l >> 3;                  // head
    const int dsub = (l & 7) << 2;         // 4 dims per lane
    const int qi = w * 1024 + 768 + n * 32 + dsub;
    float q0 = bf2f(smG[qi]), q1 = bf2f(smG[qi + 1]);
    float q2 = bf2f(smG[qi + 2]), q3 = bf2f(smG[qi + 3]);
    float sc[10];
    #pragma unroll
    for (int m = 0; m < 10; m++) {
      int idx = aidx(w * 10 + m, n * 32 + dsub);
      uint2 u = *(const uint2*)&smZ[idx];
      float p = q0 * bf2f((unsigned short)(u.x & 0xffff)) + q1 * bf2f((unsigned short)(u.x >> 16))
              + q2 * bf2f((unsigned short)(u.y & 0xffff)) + q3 * bf2f((unsigned short)(u.y >> 16));
      p += __shfl_xor(p, 1);
      p += __shfl_xor(p, 2);
      p += __shfl_xor(p, 4);
      sc[m] = p * 0.17677669529663687f;    // 1/sqrt(32)
    }
    float mx = sc[0];
    #pragma unroll
    for (int m = 1; m < 10; m++) mx = fmaxf(mx, sc[m]);
    float ssum = 0.f;
    #pragma unroll
    for (int m = 0; m < 10; m++) { sc[m] = __expf(sc[m] - mx); ssum += sc[m]; }
    float inv = 1.f / ssum;
    float myaw = 0.f;
    #pragma unroll
    for (int m = 0; m < 10; m++) {
      float a = sc[m] * inv;
      a += __shfl_xor(a, 8);
      a += __shfl_xor(a, 16);
      a += __shfl_xor(a, 32);
      a *= 0.125f;                          // mean over 8 heads
      if (l == m) myaw = a;
      if (l == 0) smAw[w][m] = a;
    }
    if (l < 10) outAw[(size_t)(b0 + w) * 10 + l] = myaw;
  }
  __syncthreads();

  // ---- P6: weighted memory -> smF rows 0..7 cols 256..511 ----
  {
    const int b = w;
    const int h0 = l << 2;
    float a0 = 0, a1 = 0, a2 = 0, a3 = 0;
    #pragma unroll
    for (int m = 0; m < 10; m++) {
      float aw = smAw[b][m];
      uint2 u = *(const uint2*)&smB2[aidx(b * 10 + m, h0)];
      a0 += aw * bf2f((unsigned short)(u.x & 0xffff));
      a1 += aw * bf2f((unsigned short)(u.x >> 16));
      a2 += aw * bf2f((unsigned short)(u.y & 0xffff));
      a3 += aw * bf2f((unsigned short)(u.y >> 16));
    }
    uint2 o;
    o.x = f2bf(a0) | ((unsigned)f2bf(a1) << 16);
    o.y = f2bf(a2) | ((unsigned)f2bf(a3) << 16);
    *(uint2*)&smF[aidx512(b, 256 + h0)] = o;
  }
  __syncthreads();

  // ---- P7: fused = LN( F[16,512] @ Wo[512,256] + bo ) ----
  float* smY = (float*)smPm;               // alias: pm no longer needed
  {
    f32x4 acc[2] = {};
    #pragma unroll
    for (int k = 0; k < 16; k++) {
      short8 a = *(const short8*)&smF[aidx512(l & 15, (k << 5) + ((l >> 4) << 3))];
      #pragma unroll
      for (int i = 0; i < 2; i++) {
        short8 b = *(const short8*)&Wop[(size_t)(((w * 2 + i) * 16 + k) * 64 + l) * 8];
        acc[i] = __builtin_amdgcn_mfma_f32_16x16x32_bf16(a, b, acc[i], 0, 0, 0);
      }
    }
    const int rloc = (l >> 4) << 2;
    #pragma unroll
    for (int i = 0; i < 2; i++) {
      int col = ((w * 2 + i) << 4) + (l & 15);   // 0..255
      float bia = bo[col];
      #pragma unroll
      for (int reg = 0; reg < 4; reg++) {
        int row = rloc + reg;
        if (row < 8) smY[row * 256 + col] = acc[i][reg] + bia;
      }
    }
  }
  __syncthreads();
  {
    float4 v = ((const float4*)smY)[w * 64 + l];   // wave w -> batch row w
    float s1 = v.x + v.y + v.z + v.w;
    float s2 = v.x * v.x + v.y * v.y + v.z * v.z + v.w * v.w;
    #pragma unroll
    for (int off = 32; off; off >>= 1) {
      s1 += __shfl_xor(s1, off);
      s2 += __shfl_xor(s2, off);
    }
    float mu = s1 * (1.f / 256.f);
    float var = s2 * (1.f / 256.f) - mu * mu;
    float rs = rsqrtf(fmaxf(var, 0.f) + 1e-5f);
    float4 g = *(const float4*)(gamma + (l << 2));
    float4 be = *(const float4*)(beta + (l << 2));
    float4 o;
    o.x = (v.x - mu) * rs * g.x + be.x;
    o.y = (v.y - mu) * rs * g.y + be.y;
    o.z = (v.z - mu) * rs * g.z + be.z;
    o.w = (v.w - mu) * rs * g.w + be.w;
    *(float4*)(outF + (size_t)(b0 + w) * 256 + (l << 2)) = o;
  }
}

extern "C" void kernel_launch(void* const* d_in, const int* in_sizes, int n_in,
                              void* d_out, int out_size, void* d_ws, size_t ws_size,
                              hipStream_t stream) {
  (void)in_sizes; (void)n_in; (void)out_size; (void)ws_size;  // ws use: 1.32 MB only
  const float* cur = (const float*)d_in[0];
  const float* pm  = (const float*)d_in[1];
  const float* Wz  = (const float*)d_in[2];
  const float* bz  = (const float*)d_in[3];
  const float* Wr  = (const float*)d_in[4];
  const float* br  = (const float*)d_in[5];
  const float* Wh  = (const float*)d_in[6];
  const float* bh  = (const float*)d_in[7];
  const float* Wq  = (const float*)d_in[8];
  const float* bq  = (const float*)d_in[9];
  const float* Wk  = (const float*)d_in[10];
  const float* bk  = (const float*)d_in[11];
  const float* Wo  = (const float*)d_in[12];
  const float* bo  = (const float*)d_in[13];
  const float* g2  = (const float*)d_in[14];
  const float* b2  = (const float*)d_in[15];

  char* ws = (char*)d_ws;
  unsigned short* wsW = (unsigned short*)ws;
  float* bias4        = (float*)(ws + OFF_B4);

  float* outF   = (float*)d_out;
  float* outUpd = outF + (size_t)BB * 256;
  float* outAw  = outUpd + (size_t)BB * MM * 256;

  hipLaunchKernelGGL(k_prep, dim3(1282), dim3(512), 0, stream,
                     Wz, Wr, Wh, Wq, Wk, Wo, bz, br, bh, bq, wsW, bias4);
  hipLaunchKernelGGL(k_fused, dim3(BB / 8), dim3(512), 0, stream,
                     cur, pm, wsW, bias4, bk, bo, g2, b2, outF, outUpd, outAw);
}